// Round 1
// baseline (1647.527 us; speedup 1.0000x reference)
//
#include <hip/hip_runtime.h>
#include <hip/hip_bf16.h>
#include <cstdint>

#define NP_PEP 50000
#define NP_PROT 8000
#define NE 1600000
#define NEL 200000
#define F_IN 1280
#define HDIM 128
#define TM 64

// ---------------- CSR build ----------------

__global__ void zero_i32(int* __restrict__ p, int n) {
    int i = blockIdx.x * blockDim.x + threadIdx.x;
    if (i < n) p[i] = 0;
}

__global__ void hist_kernel(const int* __restrict__ esrc, const int* __restrict__ edst,
                            int* __restrict__ cnt_pep, int* __restrict__ cnt_prot, int E) {
    int i = blockIdx.x * blockDim.x + threadIdx.x;
    if (i < E) {
        atomicAdd(&cnt_pep[esrc[i]], 1);
        atomicAdd(&cnt_prot[edst[i]], 1);
    }
}

// single-block chunked exclusive scan: rowptr[0..n] and cur[0..n-1] = rowptr[i]
__global__ __launch_bounds__(1024) void scan_kernel(const int* __restrict__ cnt,
                                                    int* __restrict__ rowptr,
                                                    int* __restrict__ cur, int n) {
    __shared__ int sums[1024];
    int t = threadIdx.x;
    int C = (n + 1023) >> 10;
    int lo = t * C;
    int hi = min(lo + C, n);
    int s = 0;
    for (int i = lo; i < hi; ++i) s += cnt[i];
    sums[t] = s;
    __syncthreads();
    for (int off = 1; off < 1024; off <<= 1) {
        int v = sums[t];
        int add = (t >= off) ? sums[t - off] : 0;
        __syncthreads();
        sums[t] = v + add;
        __syncthreads();
    }
    int run = sums[t] - s;   // exclusive prefix of this thread's chunk
    for (int i = lo; i < hi; ++i) {
        int c = cnt[i];
        rowptr[i] = run;
        cur[i] = run;
        run += c;
    }
    if (t == 0) rowptr[n] = sums[1023];
}

__global__ void fill_kernel(const int* __restrict__ esrc, const int* __restrict__ edst,
                            int* __restrict__ cur_pep, int* __restrict__ cur_prot,
                            int* __restrict__ col_pep, int* __restrict__ col_prot, int E) {
    int i = blockIdx.x * blockDim.x + threadIdx.x;
    if (i < E) {
        int s = esrc[i], d = edst[i];
        int p = atomicAdd(&cur_pep[s], 1);
        col_pep[p] = d;          // pep-centric CSR stores prot neighbor
        int q = atomicAdd(&cur_prot[d], 1);
        col_prot[q] = s;         // prot-centric CSR stores pep neighbor
    }
}

// ---------------- projection GEMM: C[M,128] = A[M,K] @ W[K,128] + b ----------------

__global__ __launch_bounds__(256) void gemm_proj(const float* __restrict__ A,
                                                 const float* __restrict__ W,
                                                 const float* __restrict__ bias,
                                                 float* __restrict__ C,
                                                 int M, int K) {
    __shared__ float sA[TM][36];      // 36-pad: rows stay 16B-aligned (144B)
    __shared__ float sW[32][HDIM];
    int tid = threadIdx.x;
    int tx = tid & 31, ty = tid >> 5;
    int r0 = blockIdx.x * TM;
    float4 acc[8];
#pragma unroll
    for (int i = 0; i < 8; ++i) acc[i] = make_float4(0.f, 0.f, 0.f, 0.f);

    for (int k0 = 0; k0 < K; k0 += 32) {
#pragma unroll
        for (int i = 0; i < 2; ++i) {           // A tile: 64 rows x 32 k
            int f = tid + 256 * i;
            int row = f >> 3;
            int kq = f & 7;
            int gr = min(r0 + row, M - 1);
            float4 v = *(const float4*)(A + (size_t)gr * K + k0 + kq * 4);
            *(float4*)(&sA[row][kq * 4]) = v;
        }
#pragma unroll
        for (int i = 0; i < 4; ++i) {           // W tile: 32 k x 128 n
            int f = tid + 256 * i;
            int kk = f >> 5;
            int cq = f & 31;
            *(float4*)(&sW[kk][cq * 4]) = *(const float4*)(W + (size_t)(k0 + kk) * HDIM + cq * 4);
        }
        __syncthreads();
#pragma unroll 8
        for (int kk = 0; kk < 32; ++kk) {
            float4 w = *(const float4*)(&sW[kk][tx * 4]);
#pragma unroll
            for (int i = 0; i < 8; ++i) {
                float a = sA[ty * 8 + i][kk];
                acc[i].x += a * w.x; acc[i].y += a * w.y;
                acc[i].z += a * w.z; acc[i].w += a * w.w;
            }
        }
        __syncthreads();
    }
    float4 b4 = *(const float4*)(bias + tx * 4);
#pragma unroll
    for (int i = 0; i < 8; ++i) {
        int gr = r0 + ty * 8 + i;
        if (gr < M) {
            float4 o;
            o.x = acc[i].x + b4.x; o.y = acc[i].y + b4.y;
            o.z = acc[i].z + b4.z; o.w = acc[i].w + b4.w;
            *(float4*)(C + (size_t)gr * HDIM + tx * 4) = o;
        }
    }
}

// ------- fused linear: C = A1@W1 + A2@W2 + b (+relu). C may alias A1 (per-block rows). -------

__global__ __launch_bounds__(256) void lin2_kernel(const float* A1,
                                                   const float* __restrict__ W1,
                                                   const float* __restrict__ A2,
                                                   const float* __restrict__ W2,
                                                   const float* __restrict__ bias,
                                                   float* C,
                                                   int M, int do_relu) {
    __shared__ float sA[TM][36];
    __shared__ float sW[32][HDIM];
    int tid = threadIdx.x;
    int tx = tid & 31, ty = tid >> 5;
    int r0 = blockIdx.x * TM;
    float4 acc[8];
#pragma unroll
    for (int i = 0; i < 8; ++i) acc[i] = make_float4(0.f, 0.f, 0.f, 0.f);

    for (int kt = 0; kt < 8; ++kt) {      // virtual K = 256 (A1:0-127, A2:128-255)
        const float* A = (kt < 4) ? A1 : A2;
        const float* Wm = (kt < 4) ? W1 : W2;
        int k0 = (kt & 3) * 32;
#pragma unroll
        for (int i = 0; i < 2; ++i) {
            int f = tid + 256 * i;
            int row = f >> 3;
            int kq = f & 7;
            int gr = min(r0 + row, M - 1);
            float4 v = *(const float4*)(A + (size_t)gr * HDIM + k0 + kq * 4);
            *(float4*)(&sA[row][kq * 4]) = v;
        }
#pragma unroll
        for (int i = 0; i < 4; ++i) {
            int f = tid + 256 * i;
            int kk = f >> 5;
            int cq = f & 31;
            *(float4*)(&sW[kk][cq * 4]) = *(const float4*)(Wm + (size_t)(k0 + kk) * HDIM + cq * 4);
        }
        __syncthreads();
#pragma unroll 8
        for (int kk = 0; kk < 32; ++kk) {
            float4 w = *(const float4*)(&sW[kk][tx * 4]);
#pragma unroll
            for (int i = 0; i < 8; ++i) {
                float a = sA[ty * 8 + i][kk];
                acc[i].x += a * w.x; acc[i].y += a * w.y;
                acc[i].z += a * w.z; acc[i].w += a * w.w;
            }
        }
        __syncthreads();
    }
    float4 b4 = *(const float4*)(bias + tx * 4);
#pragma unroll
    for (int i = 0; i < 8; ++i) {
        int gr = r0 + ty * 8 + i;
        if (gr < M) {
            float4 o;
            o.x = acc[i].x + b4.x; o.y = acc[i].y + b4.y;
            o.z = acc[i].z + b4.z; o.w = acc[i].w + b4.w;
            if (do_relu) {
                o.x = fmaxf(o.x, 0.f); o.y = fmaxf(o.y, 0.f);
                o.z = fmaxf(o.z, 0.f); o.w = fmaxf(o.w, 0.f);
            }
            *(float4*)(C + (size_t)gr * HDIM + tx * 4) = o;
        }
    }
}

// ---------------- mean aggregation: one wave per destination node ----------------

__global__ __launch_bounds__(256) void aggr_mean(const float* __restrict__ Hsrc,
                                                 const int* __restrict__ rowptr,
                                                 const int* __restrict__ col,
                                                 float* __restrict__ Mout, int Ndst) {
    int node = blockIdx.x * 4 + (threadIdx.x >> 6);
    if (node >= Ndst) return;
    int lane = threadIdx.x & 63;
    int half = lane >> 5, l32 = lane & 31;
    int beg = rowptr[node], end = rowptr[node + 1];
    int deg = end - beg;
    float4 acc = make_float4(0.f, 0.f, 0.f, 0.f);
    for (int j = beg + half; j < end; j += 2) {
        int idx = col[j];
        float4 v = ((const float4*)(Hsrc + (size_t)idx * HDIM))[l32];
        acc.x += v.x; acc.y += v.y; acc.z += v.z; acc.w += v.w;
    }
    acc.x += __shfl_down(acc.x, 32);
    acc.y += __shfl_down(acc.y, 32);
    acc.z += __shfl_down(acc.z, 32);
    acc.w += __shfl_down(acc.w, 32);
    if (half == 0) {
        float inv = 1.0f / (float)max(deg, 1);
        float4 o;
        o.x = acc.x * inv; o.y = acc.y * inv; o.z = acc.z * inv; o.w = acc.w * inv;
        ((float4*)(Mout + (size_t)node * HDIM))[l32] = o;
    }
}

// ---------------- classifier: 32 lanes per edge ----------------

__global__ __launch_bounds__(256) void classify_kernel(const float* __restrict__ hp,
                                                       const float* __restrict__ hr,
                                                       const int* __restrict__ esrc,
                                                       const int* __restrict__ edst,
                                                       float* __restrict__ out, int n) {
    int t = blockIdx.x * blockDim.x + threadIdx.x;
    int edge = t >> 5;
    int l = t & 31;
    if (edge >= n) return;
    int s = esrc[edge], d = edst[edge];
    float4 a = ((const float4*)(hp + (size_t)s * HDIM))[l];
    float4 b = ((const float4*)(hr + (size_t)d * HDIM))[l];
    float v = a.x * b.x + a.y * b.y + a.z * b.z + a.w * b.w;
    v += __shfl_xor(v, 16);
    v += __shfl_xor(v, 8);
    v += __shfl_xor(v, 4);
    v += __shfl_xor(v, 2);
    v += __shfl_xor(v, 1);
    if (l == 0) out[edge] = v;
}

// ---------------- launch ----------------

extern "C" void kernel_launch(void* const* d_in, const int* in_sizes, int n_in,
                              void* d_out, int out_size, void* d_ws, size_t ws_size,
                              hipStream_t stream) {
    const float* x_pep   = (const float*)d_in[0];
    const float* x_prot  = (const float*)d_in[1];
    const int*   e_src   = (const int*)d_in[2];
    const int*   e_dst   = (const int*)d_in[3];
    const int*   el_src  = (const int*)d_in[4];
    const int*   el_dst  = (const int*)d_in[5];
    const float* W_pep   = (const float*)d_in[6];
    const float* b_pep   = (const float*)d_in[7];
    const float* W_prot  = (const float*)d_in[8];
    const float* b_prot  = (const float*)d_in[9];
    const float* Wl1_bind = (const float*)d_in[10];
    const float* Wr1_bind = (const float*)d_in[11];
    const float* Wl1_rev  = (const float*)d_in[12];
    const float* Wr1_rev  = (const float*)d_in[13];
    const float* Wl2_bind = (const float*)d_in[14];
    const float* Wr2_bind = (const float*)d_in[15];
    const float* Wl2_rev  = (const float*)d_in[16];
    const float* Wr2_rev  = (const float*)d_in[17];
    const float* b1_bind  = (const float*)d_in[18];
    const float* b1_rev   = (const float*)d_in[19];
    const float* b2_bind  = (const float*)d_in[20];
    const float* b2_rev   = (const float*)d_in[21];
    float* out = (float*)d_out;

    // workspace layout (~73 MB)
    float* P0 = (float*)d_ws;                       // h0_pep -> m2_pep -> h2_pep
    float* P1 = P0 + (size_t)NP_PEP * HDIM;         // m1_pep -> h1_pep
    float* R0 = P1 + (size_t)NP_PEP * HDIM;         // h0_prot -> m2_prot -> h2_prot
    float* R1 = R0 + (size_t)NP_PROT * HDIM;        // m1_prot -> h1_prot
    int* cnt_pep    = (int*)(R1 + (size_t)NP_PROT * HDIM);
    int* cnt_prot   = cnt_pep + NP_PEP;
    int* rowptr_pep = cnt_prot + NP_PROT;
    int* rowptr_prot = rowptr_pep + NP_PEP + 1;
    int* cur_pep    = rowptr_prot + NP_PROT + 1;
    int* cur_prot   = cur_pep + NP_PEP;
    int* col_pep    = cur_prot + NP_PROT;
    int* col_prot   = col_pep + NE;

    // ---- CSR build (both directions, reused by both layers) ----
    zero_i32<<<(NP_PEP + NP_PROT + 255) / 256, 256, 0, stream>>>(cnt_pep, NP_PEP + NP_PROT);
    hist_kernel<<<(NE + 255) / 256, 256, 0, stream>>>(e_src, e_dst, cnt_pep, cnt_prot, NE);
    scan_kernel<<<1, 1024, 0, stream>>>(cnt_pep, rowptr_pep, cur_pep, NP_PEP);
    scan_kernel<<<1, 1024, 0, stream>>>(cnt_prot, rowptr_prot, cur_prot, NP_PROT);
    fill_kernel<<<(NE + 255) / 256, 256, 0, stream>>>(e_src, e_dst, cur_pep, cur_prot,
                                                      col_pep, col_prot, NE);

    // ---- input projections ----
    gemm_proj<<<(NP_PEP + TM - 1) / TM, 256, 0, stream>>>(x_pep, W_pep, b_pep, P0, NP_PEP, F_IN);
    gemm_proj<<<(NP_PROT + TM - 1) / TM, 256, 0, stream>>>(x_prot, W_prot, b_prot, R0, NP_PROT, F_IN);

    // ---- SAGE layer 1 (+relu) ----
    aggr_mean<<<(NP_PROT + 3) / 4, 256, 0, stream>>>(P0, rowptr_prot, col_prot, R1, NP_PROT);
    aggr_mean<<<(NP_PEP + 3) / 4, 256, 0, stream>>>(R0, rowptr_pep, col_pep, P1, NP_PEP);
    lin2_kernel<<<(NP_PROT + TM - 1) / TM, 256, 0, stream>>>(R1, Wl1_bind, R0, Wr1_bind, b1_bind,
                                                             R1, NP_PROT, 1);
    lin2_kernel<<<(NP_PEP + TM - 1) / TM, 256, 0, stream>>>(P1, Wl1_rev, P0, Wr1_rev, b1_rev,
                                                            P1, NP_PEP, 1);

    // ---- SAGE layer 2 ----
    aggr_mean<<<(NP_PROT + 3) / 4, 256, 0, stream>>>(P1, rowptr_prot, col_prot, R0, NP_PROT);
    aggr_mean<<<(NP_PEP + 3) / 4, 256, 0, stream>>>(R1, rowptr_pep, col_pep, P0, NP_PEP);
    lin2_kernel<<<(NP_PROT + TM - 1) / TM, 256, 0, stream>>>(R0, Wl2_bind, R1, Wr2_bind, b2_bind,
                                                             R0, NP_PROT, 0);
    lin2_kernel<<<(NP_PEP + TM - 1) / TM, 256, 0, stream>>>(P0, Wl2_rev, P1, Wr2_rev, b2_rev,
                                                            P0, NP_PEP, 0);

    // ---- classifier ----
    classify_kernel<<<(NEL * 32 + 255) / 256, 256, 0, stream>>>(P0, R0, el_src, el_dst, out, NEL);
}

// Round 2
// 1192.421 us; speedup vs baseline: 1.3817x; 1.3817x over previous
//
#include <hip/hip_runtime.h>
#include <hip/hip_bf16.h>
#include <cstdint>

#define NP_PEP 50000
#define NP_PROT 8000
#define NE 1600000
#define NEL 200000
#define F_IN 1280
#define HDIM 128

typedef __attribute__((ext_vector_type(8))) short bfrag;   // 8 bf16 (4 VGPRs)
typedef __attribute__((ext_vector_type(4))) short bhalf4;  // 4 bf16 (8 B)
typedef __attribute__((ext_vector_type(4))) float f32x4;

__device__ inline ushort f2bf(float x) {            // RNE round fp32->bf16
    union { float f; uint u; } v; v.f = x;
    uint r = v.u + 0x7FFFu + ((v.u >> 16) & 1u);
    return (ushort)(r >> 16);
}
__device__ inline void unpack2(uint u, float& lo, float& hi) {
    union { uint u; float f; } a, b;
    a.u = u << 16; b.u = u & 0xffff0000u;
    lo = a.f; hi = b.f;
}
__device__ inline uint pack2(float a, float b) {
    return (uint)f2bf(a) | ((uint)f2bf(b) << 16);
}

// ---------------- CSR build ----------------

__global__ void zero_i32(int* __restrict__ p, int n) {
    int i = blockIdx.x * blockDim.x + threadIdx.x;
    if (i < n) p[i] = 0;
}

__global__ void hist_kernel(const int* __restrict__ esrc, const int* __restrict__ edst,
                            int* __restrict__ cnt_pep, int* __restrict__ cnt_prot, int E) {
    int i = blockIdx.x * blockDim.x + threadIdx.x;
    if (i < E) {
        atomicAdd(&cnt_pep[esrc[i]], 1);
        atomicAdd(&cnt_prot[edst[i]], 1);
    }
}

__global__ __launch_bounds__(1024) void scan_kernel(const int* __restrict__ cnt,
                                                    int* __restrict__ rowptr,
                                                    int* __restrict__ cur, int n) {
    __shared__ int sums[1024];
    int t = threadIdx.x;
    int C = (n + 1023) >> 10;
    int lo = t * C;
    int hi = min(lo + C, n);
    int s = 0;
    for (int i = lo; i < hi; ++i) s += cnt[i];
    sums[t] = s;
    __syncthreads();
    for (int off = 1; off < 1024; off <<= 1) {
        int v = sums[t];
        int add = (t >= off) ? sums[t - off] : 0;
        __syncthreads();
        sums[t] = v + add;
        __syncthreads();
    }
    int run = sums[t] - s;
    for (int i = lo; i < hi; ++i) {
        int c = cnt[i];
        rowptr[i] = run;
        cur[i] = run;
        run += c;
    }
    if (t == 0) rowptr[n] = sums[1023];
}

__global__ void fill_kernel(const int* __restrict__ esrc, const int* __restrict__ edst,
                            int* __restrict__ cur_pep, int* __restrict__ cur_prot,
                            int* __restrict__ col_pep, int* __restrict__ col_prot, int E) {
    int i = blockIdx.x * blockDim.x + threadIdx.x;
    if (i < E) {
        int s = esrc[i], d = edst[i];
        int p = atomicAdd(&cur_pep[s], 1);
        col_pep[p] = d;
        int q = atomicAdd(&cur_prot[d], 1);
        col_prot[q] = s;
    }
}

// ---- shared W staging: W[k0..k0+32)[0..128) fp32 -> bf16 B-fragment layout ----
__device__ inline void stage_W(const float* __restrict__ W, ushort* Blds, int k0, int tid) {
    int n = tid & 127, g = tid >> 7;
#pragma unroll
    for (int hh = 0; hh < 2; ++hh) {
        int h = g + hh * 2;
        const float* wp = W + (size_t)(k0 + h * 8) * HDIM + n;
        bfrag p;
#pragma unroll
        for (int j = 0; j < 8; ++j) p[j] = (short)f2bf(wp[(size_t)j * HDIM]);
        *(bfrag*)&Blds[((n >> 4) * 64 + (h << 4) + (n & 15)) * 8] = p;
    }
}

// -------- projection: C[M,128](bf16) = A[M,K](f32) @ W[K,128](f32) + b --------
__global__ __launch_bounds__(256) void gemm_proj_mfma(const float* __restrict__ A,
                                                      const float* __restrict__ W,
                                                      const float* __restrict__ bias,
                                                      ushort* __restrict__ Cg,
                                                      int M, int K) {
    __shared__ ushort Alds[4096];        // 8 m-tiles x 64 lanes x 8 bf16
    __shared__ ushort Blds[4096];        // 8 n-tiles x 64 lanes x 8 bf16
    __shared__ ushort Clds[128 * 136];   // bf16 C-stage, padded stride
    int tid = threadIdx.x;
    int lane = tid & 63, w = tid >> 6, wm = w >> 1, wn = w & 1;
    int r0 = blockIdx.x * 128;

    f32x4 acc[4][4];
#pragma unroll
    for (int i = 0; i < 4; ++i)
#pragma unroll
        for (int j = 0; j < 4; ++j) acc[i][j] = (f32x4){0.f, 0.f, 0.f, 0.f};

    for (int k0 = 0; k0 < K; k0 += 32) {
        // A tile: 128 rows x 32 k fp32 -> bf16 fragment order
#pragma unroll
        for (int i = 0; i < 4; ++i) {
            int idx = tid + 256 * i;          // 1024 float4s
            int row = idx >> 3, q = idx & 7;
            int gr = min(r0 + row, M - 1);
            float4 v = *(const float4*)(A + (size_t)gr * K + k0 + q * 4);
            bhalf4 p;
            p.x = (short)f2bf(v.x); p.y = (short)f2bf(v.y);
            p.z = (short)f2bf(v.z); p.w = (short)f2bf(v.w);
            int off = ((row >> 4) * 64 + ((q >> 1) << 4) + (row & 15)) * 8 + (q & 1) * 4;
            *(bhalf4*)&Alds[off] = p;
        }
        stage_W(W, Blds, k0, tid);
        __syncthreads();
        const bfrag* Af = (const bfrag*)Alds;
        const bfrag* Bf = (const bfrag*)Blds;
        bfrag af[4], bf_[4];
#pragma unroll
        for (int i = 0; i < 4; ++i) af[i] = Af[(wm * 4 + i) * 64 + lane];
#pragma unroll
        for (int j = 0; j < 4; ++j) bf_[j] = Bf[(wn * 4 + j) * 64 + lane];
#pragma unroll
        for (int i = 0; i < 4; ++i)
#pragma unroll
            for (int j = 0; j < 4; ++j)
                acc[i][j] = __builtin_amdgcn_mfma_f32_16x16x32_bf16(af[i], bf_[j], acc[i][j], 0, 0, 0);
        __syncthreads();
    }
    // epilogue: bias + bf16 via LDS transpose, coalesced store
#pragma unroll
    for (int j = 0; j < 4; ++j) {
        int colL = wn * 64 + j * 16 + (lane & 15);
        float bcol = bias[colL];
#pragma unroll
        for (int i = 0; i < 4; ++i) {
            int rbase = wm * 64 + i * 16 + ((lane >> 4) << 2);
            f32x4 v = acc[i][j];
            Clds[(rbase + 0) * 136 + colL] = f2bf(v.x + bcol);
            Clds[(rbase + 1) * 136 + colL] = f2bf(v.y + bcol);
            Clds[(rbase + 2) * 136 + colL] = f2bf(v.z + bcol);
            Clds[(rbase + 3) * 136 + colL] = f2bf(v.w + bcol);
        }
    }
    __syncthreads();
#pragma unroll
    for (int c = 0; c < 8; ++c) {
        int cidx = c * 256 + tid;
        int row = cidx >> 4, h = cidx & 15;
        int gr = r0 + row;
        if (gr < M)
            *(bfrag*)(Cg + (size_t)gr * HDIM + h * 8) = *(const bfrag*)&Clds[row * 136 + h * 8];
    }
}

// ---- fused linear (bf16): C = A1@W1 + A2@W2 + b (+relu). C may alias A1. ----
__global__ __launch_bounds__(256) void lin2_mfma(const ushort* A1,
                                                 const float* __restrict__ W1,
                                                 const ushort* A2,
                                                 const float* __restrict__ W2,
                                                 const float* __restrict__ bias,
                                                 ushort* C, int M, int do_relu) {
    __shared__ ushort Alds[4096];
    __shared__ ushort Blds[4096];
    __shared__ ushort Clds[128 * 136];
    int tid = threadIdx.x;
    int lane = tid & 63, w = tid >> 6, wm = w >> 1, wn = w & 1;
    int r0 = blockIdx.x * 128;

    f32x4 acc[4][4];
#pragma unroll
    for (int i = 0; i < 4; ++i)
#pragma unroll
        for (int j = 0; j < 4; ++j) acc[i][j] = (f32x4){0.f, 0.f, 0.f, 0.f};

    for (int kt = 0; kt < 8; ++kt) {          // virtual K=256
        const ushort* A = (kt < 4) ? A1 : A2;
        const float* Wm = (kt < 4) ? W1 : W2;
        int k0 = (kt & 3) * 32;
        // A tile: bf16 source, direct fragment copy (16B per chunk)
#pragma unroll
        for (int i = 0; i < 2; ++i) {
            int idx = tid + 256 * i;          // 512 chunks
            int row = idx >> 2, h = idx & 3;
            int gr = min(r0 + row, M - 1);
            *(bfrag*)&Alds[((row >> 4) * 64 + (h << 4) + (row & 15)) * 8] =
                *(const bfrag*)(A + (size_t)gr * HDIM + k0 + h * 8);
        }
        stage_W(Wm, Blds, k0, tid);
        __syncthreads();
        const bfrag* Af = (const bfrag*)Alds;
        const bfrag* Bf = (const bfrag*)Blds;
        bfrag af[4], bf_[4];
#pragma unroll
        for (int i = 0; i < 4; ++i) af[i] = Af[(wm * 4 + i) * 64 + lane];
#pragma unroll
        for (int j = 0; j < 4; ++j) bf_[j] = Bf[(wn * 4 + j) * 64 + lane];
#pragma unroll
        for (int i = 0; i < 4; ++i)
#pragma unroll
            for (int j = 0; j < 4; ++j)
                acc[i][j] = __builtin_amdgcn_mfma_f32_16x16x32_bf16(af[i], bf_[j], acc[i][j], 0, 0, 0);
        __syncthreads();
    }
#pragma unroll
    for (int j = 0; j < 4; ++j) {
        int colL = wn * 64 + j * 16 + (lane & 15);
        float bcol = bias[colL];
#pragma unroll
        for (int i = 0; i < 4; ++i) {
            int rbase = wm * 64 + i * 16 + ((lane >> 4) << 2);
            f32x4 v = acc[i][j];
            float o0 = v.x + bcol, o1 = v.y + bcol, o2 = v.z + bcol, o3 = v.w + bcol;
            if (do_relu) {
                o0 = fmaxf(o0, 0.f); o1 = fmaxf(o1, 0.f);
                o2 = fmaxf(o2, 0.f); o3 = fmaxf(o3, 0.f);
            }
            Clds[(rbase + 0) * 136 + colL] = f2bf(o0);
            Clds[(rbase + 1) * 136 + colL] = f2bf(o1);
            Clds[(rbase + 2) * 136 + colL] = f2bf(o2);
            Clds[(rbase + 3) * 136 + colL] = f2bf(o3);
        }
    }
    __syncthreads();
#pragma unroll
    for (int c = 0; c < 8; ++c) {
        int cidx = c * 256 + tid;
        int row = cidx >> 4, h = cidx & 15;
        int gr = r0 + row;
        if (gr < M)
            *(bfrag*)(C + (size_t)gr * HDIM + h * 8) = *(const bfrag*)&Clds[row * 136 + h * 8];
    }
}

// ------- mean aggregation (bf16 tables): one wave per dst node, 4 edges/iter -------
__global__ __launch_bounds__(256) void aggr_mean_bf16(const ushort* __restrict__ Hsrc,
                                                      const int* __restrict__ rowptr,
                                                      const int* __restrict__ col,
                                                      ushort* __restrict__ Mout, int Ndst) {
    int node = blockIdx.x * 4 + (threadIdx.x >> 6);
    if (node >= Ndst) return;
    int lane = threadIdx.x & 63;
    int sub = lane >> 4;       // edge slot 0..3
    int ch = lane & 15;        // 16B chunk within row
    int beg = rowptr[node], end = rowptr[node + 1];
    int deg = end - beg;
    float a0 = 0, a1 = 0, a2 = 0, a3 = 0, a4 = 0, a5 = 0, a6 = 0, a7 = 0;
    for (int j = beg + sub; j < end; j += 4) {
        int idx = col[j];
        uint4 u = *(const uint4*)(Hsrc + (size_t)idx * HDIM + ch * 8);
        float lo, hi;
        unpack2(u.x, lo, hi); a0 += lo; a1 += hi;
        unpack2(u.y, lo, hi); a2 += lo; a3 += hi;
        unpack2(u.z, lo, hi); a4 += lo; a5 += hi;
        unpack2(u.w, lo, hi); a6 += lo; a7 += hi;
    }
    a0 += __shfl_xor(a0, 16); a0 += __shfl_xor(a0, 32);
    a1 += __shfl_xor(a1, 16); a1 += __shfl_xor(a1, 32);
    a2 += __shfl_xor(a2, 16); a2 += __shfl_xor(a2, 32);
    a3 += __shfl_xor(a3, 16); a3 += __shfl_xor(a3, 32);
    a4 += __shfl_xor(a4, 16); a4 += __shfl_xor(a4, 32);
    a5 += __shfl_xor(a5, 16); a5 += __shfl_xor(a5, 32);
    a6 += __shfl_xor(a6, 16); a6 += __shfl_xor(a6, 32);
    a7 += __shfl_xor(a7, 16); a7 += __shfl_xor(a7, 32);
    if (sub == 0) {
        float inv = 1.0f / (float)max(deg, 1);
        uint4 o;
        o.x = pack2(a0 * inv, a1 * inv);
        o.y = pack2(a2 * inv, a3 * inv);
        o.z = pack2(a4 * inv, a5 * inv);
        o.w = pack2(a6 * inv, a7 * inv);
        *(uint4*)(Mout + (size_t)node * HDIM + ch * 8) = o;
    }
}

// ---------------- classifier (bf16 tables): 16 lanes per edge ----------------
__global__ __launch_bounds__(256) void classify_bf16(const ushort* __restrict__ hp,
                                                     const ushort* __restrict__ hr,
                                                     const int* __restrict__ esrc,
                                                     const int* __restrict__ edst,
                                                     float* __restrict__ out, int n) {
    int t = blockIdx.x * blockDim.x + threadIdx.x;
    int edge = t >> 4;
    int ch = t & 15;
    if (edge >= n) return;
    int s = esrc[edge], d = edst[edge];
    uint4 ua = *(const uint4*)(hp + (size_t)s * HDIM + ch * 8);
    uint4 ub = *(const uint4*)(hr + (size_t)d * HDIM + ch * 8);
    float al, ah, bl, bh;
    float v = 0.f;
    unpack2(ua.x, al, ah); unpack2(ub.x, bl, bh); v += al * bl + ah * bh;
    unpack2(ua.y, al, ah); unpack2(ub.y, bl, bh); v += al * bl + ah * bh;
    unpack2(ua.z, al, ah); unpack2(ub.z, bl, bh); v += al * bl + ah * bh;
    unpack2(ua.w, al, ah); unpack2(ub.w, bl, bh); v += al * bl + ah * bh;
    v += __shfl_xor(v, 8);
    v += __shfl_xor(v, 4);
    v += __shfl_xor(v, 2);
    v += __shfl_xor(v, 1);
    if (ch == 0) out[edge] = v;
}

// ---------------- launch ----------------

extern "C" void kernel_launch(void* const* d_in, const int* in_sizes, int n_in,
                              void* d_out, int out_size, void* d_ws, size_t ws_size,
                              hipStream_t stream) {
    const float* x_pep   = (const float*)d_in[0];
    const float* x_prot  = (const float*)d_in[1];
    const int*   e_src   = (const int*)d_in[2];
    const int*   e_dst   = (const int*)d_in[3];
    const int*   el_src  = (const int*)d_in[4];
    const int*   el_dst  = (const int*)d_in[5];
    const float* W_pep   = (const float*)d_in[6];
    const float* b_pep   = (const float*)d_in[7];
    const float* W_prot  = (const float*)d_in[8];
    const float* b_prot  = (const float*)d_in[9];
    const float* Wl1_bind = (const float*)d_in[10];
    const float* Wr1_bind = (const float*)d_in[11];
    const float* Wl1_rev  = (const float*)d_in[12];
    const float* Wr1_rev  = (const float*)d_in[13];
    const float* Wl2_bind = (const float*)d_in[14];
    const float* Wr2_bind = (const float*)d_in[15];
    const float* Wl2_rev  = (const float*)d_in[16];
    const float* Wr2_rev  = (const float*)d_in[17];
    const float* b1_bind  = (const float*)d_in[18];
    const float* b1_rev   = (const float*)d_in[19];
    const float* b2_bind  = (const float*)d_in[20];
    const float* b2_rev   = (const float*)d_in[21];
    float* out = (float*)d_out;

    // workspace: bf16 node tables then CSR ints
    ushort* P0 = (ushort*)d_ws;                     // h0_pep -> m2_pep -> h2_pep
    ushort* P1 = P0 + (size_t)NP_PEP * HDIM;        // m1_pep -> h1_pep
    ushort* R0 = P1 + (size_t)NP_PEP * HDIM;        // h0_prot -> m2_prot -> h2_prot
    ushort* R1 = R0 + (size_t)NP_PROT * HDIM;       // m1_prot -> h1_prot
    int* cnt_pep     = (int*)(R1 + (size_t)NP_PROT * HDIM);
    int* cnt_prot    = cnt_pep + NP_PEP;
    int* rowptr_pep  = cnt_prot + NP_PROT;
    int* rowptr_prot = rowptr_pep + NP_PEP + 1;
    int* cur_pep     = rowptr_prot + NP_PROT + 1;
    int* cur_prot    = cur_pep + NP_PEP;
    int* col_pep     = cur_prot + NP_PROT;
    int* col_prot    = col_pep + NE;

    // ---- CSR build ----
    zero_i32<<<(NP_PEP + NP_PROT + 255) / 256, 256, 0, stream>>>(cnt_pep, NP_PEP + NP_PROT);
    hist_kernel<<<(NE + 255) / 256, 256, 0, stream>>>(e_src, e_dst, cnt_pep, cnt_prot, NE);
    scan_kernel<<<1, 1024, 0, stream>>>(cnt_pep, rowptr_pep, cur_pep, NP_PEP);
    scan_kernel<<<1, 1024, 0, stream>>>(cnt_prot, rowptr_prot, cur_prot, NP_PROT);
    fill_kernel<<<(NE + 255) / 256, 256, 0, stream>>>(e_src, e_dst, cur_pep, cur_prot,
                                                      col_pep, col_prot, NE);

    // ---- input projections (fp32 in, bf16 out, MFMA) ----
    gemm_proj_mfma<<<(NP_PEP + 127) / 128, 256, 0, stream>>>(x_pep, W_pep, b_pep, P0, NP_PEP, F_IN);
    gemm_proj_mfma<<<(NP_PROT + 127) / 128, 256, 0, stream>>>(x_prot, W_prot, b_prot, R0, NP_PROT, F_IN);

    // ---- SAGE layer 1 (+relu) ----
    aggr_mean_bf16<<<(NP_PROT + 3) / 4, 256, 0, stream>>>(P0, rowptr_prot, col_prot, R1, NP_PROT);
    aggr_mean_bf16<<<(NP_PEP + 3) / 4, 256, 0, stream>>>(R0, rowptr_pep, col_pep, P1, NP_PEP);
    lin2_mfma<<<(NP_PROT + 127) / 128, 256, 0, stream>>>(R1, Wl1_bind, R0, Wr1_bind, b1_bind,
                                                         R1, NP_PROT, 1);
    lin2_mfma<<<(NP_PEP + 127) / 128, 256, 0, stream>>>(P1, Wl1_rev, P0, Wr1_rev, b1_rev,
                                                        P1, NP_PEP, 1);

    // ---- SAGE layer 2 ----
    aggr_mean_bf16<<<(NP_PROT + 3) / 4, 256, 0, stream>>>(P1, rowptr_prot, col_prot, R0, NP_PROT);
    aggr_mean_bf16<<<(NP_PEP + 3) / 4, 256, 0, stream>>>(R1, rowptr_pep, col_pep, P0, NP_PEP);
    lin2_mfma<<<(NP_PROT + 127) / 128, 256, 0, stream>>>(R0, Wl2_bind, R1, Wr2_bind, b2_bind,
                                                         R0, NP_PROT, 0);
    lin2_mfma<<<(NP_PEP + 127) / 128, 256, 0, stream>>>(P0, Wl2_rev, P1, Wr2_rev, b2_rev,
                                                        P0, NP_PEP, 0);

    // ---- classifier ----
    classify_bf16<<<(NEL * 16 + 255) / 256, 256, 0, stream>>>(P0, R0, el_src, el_dst, out, NEL);
}

// Round 3
// 1032.247 us; speedup vs baseline: 1.5961x; 1.1552x over previous
//
#include <hip/hip_runtime.h>
#include <hip/hip_bf16.h>
#include <cstdint>

#define NP_PEP 50000
#define NP_PROT 8000
#define NE 1600000
#define NEL 200000
#define F_IN 1280
#define HDIM 128

// CSR binning constants
#define CHUNK 4096
#define NBLK 391            // ceil(NE/CHUNK)
#define NBQ 500             // prot buckets (16 nodes each, d>>4)
#define SHQ 4
#define NBP 391             // pep buckets (128 nodes each, s>>7)
#define SHP 7

typedef __attribute__((ext_vector_type(8))) short bfrag;   // 8 bf16 (4 VGPRs)
typedef __attribute__((ext_vector_type(4))) short bhalf4;  // 4 bf16 (8 B)
typedef __attribute__((ext_vector_type(4))) float f32x4;

__device__ inline ushort f2bf(float x) {            // RNE round fp32->bf16
    union { float f; uint u; } v; v.f = x;
    uint r = v.u + 0x7FFFu + ((v.u >> 16) & 1u);
    return (ushort)(r >> 16);
}
__device__ inline void unpack2(uint u, float& lo, float& hi) {
    union { uint u; float f; } a, b;
    a.u = u << 16; b.u = u & 0xffff0000u;
    lo = a.f; hi = b.f;
}
__device__ inline uint pack2(float a, float b) {
    return (uint)f2bf(a) | ((uint)f2bf(b) << 16);
}

// ---------------- CSR build ----------------

__global__ void zero_i32(int* __restrict__ p, int n) {
    int i = blockIdx.x * blockDim.x + threadIdx.x;
    if (i < n) p[i] = 0;
}

__global__ void hist_kernel(const int* __restrict__ esrc, const int* __restrict__ edst,
                            int* __restrict__ cnt_pep, int* __restrict__ cnt_prot, int E) {
    int i = blockIdx.x * blockDim.x + threadIdx.x;
    if (i < E) {
        atomicAdd(&cnt_pep[esrc[i]], 1);   // non-returning: fire-and-forget
        atomicAdd(&cnt_prot[edst[i]], 1);
    }
}

__global__ __launch_bounds__(1024) void scan_kernel(const int* __restrict__ cnt,
                                                    int* __restrict__ rowptr,
                                                    int* __restrict__ cur, int n) {
    __shared__ int sums[1024];
    int t = threadIdx.x;
    int C = (n + 1023) >> 10;
    int lo = t * C;
    int hi = min(lo + C, n);
    int s = 0;
    for (int i = lo; i < hi; ++i) s += cnt[i];
    sums[t] = s;
    __syncthreads();
    for (int off = 1; off < 1024; off <<= 1) {
        int v = sums[t];
        int add = (t >= off) ? sums[t - off] : 0;
        __syncthreads();
        sums[t] = v + add;
        __syncthreads();
    }
    int run = sums[t] - s;
    for (int i = lo; i < hi; ++i) {
        int c = cnt[i];
        rowptr[i] = run;
        cur[i] = run;
        run += c;
    }
    if (t == 0) rowptr[n] = sums[1023];
}

// per-block bucket histograms for both directions; G layout [bucket][block]
__global__ __launch_bounds__(512) void bin_count(const int* __restrict__ esrc,
                                                 const int* __restrict__ edst,
                                                 int* __restrict__ Gq,   // [NBQ][NBLK]
                                                 int* __restrict__ Gp) { // [NBP][NBLK]
    __shared__ int hq[NBQ];
    __shared__ int hp[NBP];
    int b = blockIdx.x, t = threadIdx.x;
    if (t < NBQ) hq[t] = 0;
    if (t < NBP) hp[t] = 0;
    __syncthreads();
    int e0 = b * CHUNK, cnt = min(CHUNK, NE - e0);
#pragma unroll
    for (int r = 0; r < 8; ++r) {
        int i = t + r * 512;
        if (i < cnt) {
            atomicAdd(&hq[edst[e0 + i] >> SHQ], 1);
            atomicAdd(&hp[esrc[e0 + i] >> SHP], 1);
        }
    }
    __syncthreads();
    if (t < NBQ) Gq[t * NBLK + b] = hq[t];
    if (t < NBP) Gp[t * NBLK + b] = hp[t];
}

// per-bucket exclusive scan over blocks: O[j][b] = rowptr[j*npb] + sum_{b'<b} G[j][b']
__global__ __launch_bounds__(512) void bucket_offsets(const int* __restrict__ rowptr,
                                                      const int* __restrict__ G,
                                                      int* __restrict__ O, int npb) {
    int j = blockIdx.x, t = threadIdx.x;
    __shared__ int sh[512];
    int v = (t < NBLK) ? G[j * NBLK + t] : 0;
    sh[t] = v;
    __syncthreads();
    for (int off = 1; off < 512; off <<= 1) {
        int a = sh[t];
        int c = (t >= off) ? sh[t - off] : 0;
        __syncthreads();
        sh[t] = a + c;
        __syncthreads();
    }
    int excl = sh[t] - v;
    if (t < NBLK) O[j * NBLK + t] = rowptr[j * npb] + excl;
}

// LDS counting-sort of a 4096-edge chunk by bucket; coalesced copy-out to staging
__global__ __launch_bounds__(512) void bin_scatter(const int* __restrict__ esrc,
                                                   const int* __restrict__ edst,
                                                   const int* __restrict__ O,
                                                   uint* __restrict__ staging,
                                                   int bshift, int use_dst) {
    __shared__ int hist[512];
    __shared__ int start[512];
    __shared__ uint sorted[CHUNK];
    int b = blockIdx.x, t = threadIdx.x;
    int e0 = b * CHUNK, cnt = min(CHUNK, NE - e0);
    hist[t] = 0;
    __syncthreads();
    uint pk[8];
    int bk[8];
#pragma unroll
    for (int r = 0; r < 8; ++r) {
        int i = t + r * 512;
        bk[r] = -1;
        if (i < cnt) {
            int s = esrc[e0 + i], d = edst[e0 + i];
            pk[r] = ((uint)s << 13) | (uint)d;
            int key = use_dst ? d : s;
            bk[r] = key >> bshift;
            atomicAdd(&hist[bk[r]], 1);
        }
    }
    __syncthreads();
    int ownv = hist[t];
    start[t] = ownv;
    __syncthreads();
    for (int off = 1; off < 512; off <<= 1) {
        int a = start[t];
        int c = (t >= off) ? start[t - off] : 0;
        __syncthreads();
        start[t] = a + c;
        __syncthreads();
    }
    int excl = start[t] - ownv;
    start[t] = excl;        // exclusive prefix (own slot only)
    hist[t] = excl;         // running cursor
    __syncthreads();
#pragma unroll
    for (int r = 0; r < 8; ++r)
        if (bk[r] >= 0) {
            int rank = atomicAdd(&hist[bk[r]], 1);
            sorted[rank] = pk[r];
        }
    __syncthreads();
#pragma unroll
    for (int r = 0; r < 8; ++r) {
        int i = t + r * 512;
        if (i < cnt) {
            uint v = sorted[i];
            int key = use_dst ? (int)(v & 8191u) : (int)(v >> 13);
            int bb = key >> bshift;
            staging[O[bb * NBLK + b] + (i - start[bb])] = v;
        }
    }
}

// one block per bucket: LDS node cursors, localized col writes, zero global atomics
__global__ __launch_bounds__(256) void bin_place(const uint* __restrict__ staging,
                                                 const int* __restrict__ rowptr,
                                                 int* __restrict__ col,
                                                 int n, int npb, int use_dst) {
    int j = blockIdx.x, t = threadIdx.x;
    __shared__ int cur[128];
    int first = j * npb;
    int nn = min(npb, n - first);
    if (t < nn) cur[t] = rowptr[first + t];
    __syncthreads();
    int base = rowptr[first];
    int segend = rowptr[min(first + npb, n)];
    for (int i = base + t; i < segend; i += 256) {
        uint v = staging[i];
        int key = use_dst ? (int)(v & 8191u) : (int)(v >> 13);
        int pay = use_dst ? (int)(v >> 13) : (int)(v & 8191u);
        int pos = atomicAdd(&cur[key - first], 1);
        col[pos] = pay;
    }
}

// ---- shared W staging: W[k0..k0+32)[0..128) fp32 -> bf16 B-fragment layout ----
__device__ inline void stage_W(const float* __restrict__ W, ushort* Blds, int k0, int tid) {
    int n = tid & 127, g = tid >> 7;
#pragma unroll
    for (int hh = 0; hh < 2; ++hh) {
        int h = g + hh * 2;
        const float* wp = W + (size_t)(k0 + h * 8) * HDIM + n;
        bfrag p;
#pragma unroll
        for (int j = 0; j < 8; ++j) p[j] = (short)f2bf(wp[(size_t)j * HDIM]);
        *(bfrag*)&Blds[((n >> 4) * 64 + (h << 4) + (n & 15)) * 8] = p;
    }
}

// -------- projection: C[M,128](bf16) = A[M,K](f32) @ W[K,128](f32) + b --------
__global__ __launch_bounds__(256) void gemm_proj_mfma(const float* __restrict__ A,
                                                      const float* __restrict__ W,
                                                      const float* __restrict__ bias,
                                                      ushort* __restrict__ Cg,
                                                      int M, int K) {
    __shared__ ushort Alds[4096];
    __shared__ ushort Blds[4096];
    __shared__ ushort Clds[128 * 136];
    int tid = threadIdx.x;
    int lane = tid & 63, w = tid >> 6, wm = w >> 1, wn = w & 1;
    int r0 = blockIdx.x * 128;

    f32x4 acc[4][4];
#pragma unroll
    for (int i = 0; i < 4; ++i)
#pragma unroll
        for (int j = 0; j < 4; ++j) acc[i][j] = (f32x4){0.f, 0.f, 0.f, 0.f};

    for (int k0 = 0; k0 < K; k0 += 32) {
#pragma unroll
        for (int i = 0; i < 4; ++i) {
            int idx = tid + 256 * i;
            int row = idx >> 3, q = idx & 7;
            int gr = min(r0 + row, M - 1);
            float4 v = *(const float4*)(A + (size_t)gr * K + k0 + q * 4);
            bhalf4 p;
            p.x = (short)f2bf(v.x); p.y = (short)f2bf(v.y);
            p.z = (short)f2bf(v.z); p.w = (short)f2bf(v.w);
            int off = ((row >> 4) * 64 + ((q >> 1) << 4) + (row & 15)) * 8 + (q & 1) * 4;
            *(bhalf4*)&Alds[off] = p;
        }
        stage_W(W, Blds, k0, tid);
        __syncthreads();
        const bfrag* Af = (const bfrag*)Alds;
        const bfrag* Bf = (const bfrag*)Blds;
        bfrag af[4], bf_[4];
#pragma unroll
        for (int i = 0; i < 4; ++i) af[i] = Af[(wm * 4 + i) * 64 + lane];
#pragma unroll
        for (int j = 0; j < 4; ++j) bf_[j] = Bf[(wn * 4 + j) * 64 + lane];
#pragma unroll
        for (int i = 0; i < 4; ++i)
#pragma unroll
            for (int j = 0; j < 4; ++j)
                acc[i][j] = __builtin_amdgcn_mfma_f32_16x16x32_bf16(af[i], bf_[j], acc[i][j], 0, 0, 0);
        __syncthreads();
    }
#pragma unroll
    for (int j = 0; j < 4; ++j) {
        int colL = wn * 64 + j * 16 + (lane & 15);
        float bcol = bias[colL];
#pragma unroll
        for (int i = 0; i < 4; ++i) {
            int rbase = wm * 64 + i * 16 + ((lane >> 4) << 2);
            f32x4 v = acc[i][j];
            Clds[(rbase + 0) * 136 + colL] = f2bf(v.x + bcol);
            Clds[(rbase + 1) * 136 + colL] = f2bf(v.y + bcol);
            Clds[(rbase + 2) * 136 + colL] = f2bf(v.z + bcol);
            Clds[(rbase + 3) * 136 + colL] = f2bf(v.w + bcol);
        }
    }
    __syncthreads();
#pragma unroll
    for (int c = 0; c < 8; ++c) {
        int cidx = c * 256 + tid;
        int row = cidx >> 4, h = cidx & 15;
        int gr = r0 + row;
        if (gr < M)
            *(bfrag*)(Cg + (size_t)gr * HDIM + h * 8) = *(const bfrag*)&Clds[row * 136 + h * 8];
    }
}

// ---- fused linear (bf16): C = A1@W1 + A2@W2 + b (+relu). C may alias A1. ----
__global__ __launch_bounds__(256) void lin2_mfma(const ushort* A1,
                                                 const float* __restrict__ W1,
                                                 const ushort* A2,
                                                 const float* __restrict__ W2,
                                                 const float* __restrict__ bias,
                                                 ushort* C, int M, int do_relu) {
    __shared__ ushort Alds[4096];
    __shared__ ushort Blds[4096];
    __shared__ ushort Clds[128 * 136];
    int tid = threadIdx.x;
    int lane = tid & 63, w = tid >> 6, wm = w >> 1, wn = w & 1;
    int r0 = blockIdx.x * 128;

    f32x4 acc[4][4];
#pragma unroll
    for (int i = 0; i < 4; ++i)
#pragma unroll
        for (int j = 0; j < 4; ++j) acc[i][j] = (f32x4){0.f, 0.f, 0.f, 0.f};

    for (int kt = 0; kt < 8; ++kt) {
        const ushort* A = (kt < 4) ? A1 : A2;
        const float* Wm = (kt < 4) ? W1 : W2;
        int k0 = (kt & 3) * 32;
#pragma unroll
        for (int i = 0; i < 2; ++i) {
            int idx = tid + 256 * i;
            int row = idx >> 2, h = idx & 3;
            int gr = min(r0 + row, M - 1);
            *(bfrag*)&Alds[((row >> 4) * 64 + (h << 4) + (row & 15)) * 8] =
                *(const bfrag*)(A + (size_t)gr * HDIM + k0 + h * 8);
        }
        stage_W(Wm, Blds, k0, tid);
        __syncthreads();
        const bfrag* Af = (const bfrag*)Alds;
        const bfrag* Bf = (const bfrag*)Blds;
        bfrag af[4], bf_[4];
#pragma unroll
        for (int i = 0; i < 4; ++i) af[i] = Af[(wm * 4 + i) * 64 + lane];
#pragma unroll
        for (int j = 0; j < 4; ++j) bf_[j] = Bf[(wn * 4 + j) * 64 + lane];
#pragma unroll
        for (int i = 0; i < 4; ++i)
#pragma unroll
            for (int j = 0; j < 4; ++j)
                acc[i][j] = __builtin_amdgcn_mfma_f32_16x16x32_bf16(af[i], bf_[j], acc[i][j], 0, 0, 0);
        __syncthreads();
    }
#pragma unroll
    for (int j = 0; j < 4; ++j) {
        int colL = wn * 64 + j * 16 + (lane & 15);
        float bcol = bias[colL];
#pragma unroll
        for (int i = 0; i < 4; ++i) {
            int rbase = wm * 64 + i * 16 + ((lane >> 4) << 2);
            f32x4 v = acc[i][j];
            float o0 = v.x + bcol, o1 = v.y + bcol, o2 = v.z + bcol, o3 = v.w + bcol;
            if (do_relu) {
                o0 = fmaxf(o0, 0.f); o1 = fmaxf(o1, 0.f);
                o2 = fmaxf(o2, 0.f); o3 = fmaxf(o3, 0.f);
            }
            Clds[(rbase + 0) * 136 + colL] = f2bf(o0);
            Clds[(rbase + 1) * 136 + colL] = f2bf(o1);
            Clds[(rbase + 2) * 136 + colL] = f2bf(o2);
            Clds[(rbase + 3) * 136 + colL] = f2bf(o3);
        }
    }
    __syncthreads();
#pragma unroll
    for (int c = 0; c < 8; ++c) {
        int cidx = c * 256 + tid;
        int row = cidx >> 4, h = cidx & 15;
        int gr = r0 + row;
        if (gr < M)
            *(bfrag*)(C + (size_t)gr * HDIM + h * 8) = *(const bfrag*)&Clds[row * 136 + h * 8];
    }
}

// ------- mean aggregation (bf16 tables): one wave per dst node, 4 edges/iter -------
__global__ __launch_bounds__(256) void aggr_mean_bf16(const ushort* __restrict__ Hsrc,
                                                      const int* __restrict__ rowptr,
                                                      const int* __restrict__ col,
                                                      ushort* __restrict__ Mout, int Ndst) {
    int node = blockIdx.x * 4 + (threadIdx.x >> 6);
    if (node >= Ndst) return;
    int lane = threadIdx.x & 63;
    int sub = lane >> 4;
    int ch = lane & 15;
    int beg = rowptr[node], end = rowptr[node + 1];
    int deg = end - beg;
    float a0 = 0, a1 = 0, a2 = 0, a3 = 0, a4 = 0, a5 = 0, a6 = 0, a7 = 0;
    for (int j = beg + sub; j < end; j += 4) {
        int idx = col[j];
        uint4 u = *(const uint4*)(Hsrc + (size_t)idx * HDIM + ch * 8);
        float lo, hi;
        unpack2(u.x, lo, hi); a0 += lo; a1 += hi;
        unpack2(u.y, lo, hi); a2 += lo; a3 += hi;
        unpack2(u.z, lo, hi); a4 += lo; a5 += hi;
        unpack2(u.w, lo, hi); a6 += lo; a7 += hi;
    }
    a0 += __shfl_xor(a0, 16); a0 += __shfl_xor(a0, 32);
    a1 += __shfl_xor(a1, 16); a1 += __shfl_xor(a1, 32);
    a2 += __shfl_xor(a2, 16); a2 += __shfl_xor(a2, 32);
    a3 += __shfl_xor(a3, 16); a3 += __shfl_xor(a3, 32);
    a4 += __shfl_xor(a4, 16); a4 += __shfl_xor(a4, 32);
    a5 += __shfl_xor(a5, 16); a5 += __shfl_xor(a5, 32);
    a6 += __shfl_xor(a6, 16); a6 += __shfl_xor(a6, 32);
    a7 += __shfl_xor(a7, 16); a7 += __shfl_xor(a7, 32);
    if (sub == 0) {
        float inv = 1.0f / (float)max(deg, 1);
        uint4 o;
        o.x = pack2(a0 * inv, a1 * inv);
        o.y = pack2(a2 * inv, a3 * inv);
        o.z = pack2(a4 * inv, a5 * inv);
        o.w = pack2(a6 * inv, a7 * inv);
        *(uint4*)(Mout + (size_t)node * HDIM + ch * 8) = o;
    }
}

// ---------------- classifier (bf16 tables): 16 lanes per edge ----------------
__global__ __launch_bounds__(256) void classify_bf16(const ushort* __restrict__ hp,
                                                     const ushort* __restrict__ hr,
                                                     const int* __restrict__ esrc,
                                                     const int* __restrict__ edst,
                                                     float* __restrict__ out, int n) {
    int t = blockIdx.x * blockDim.x + threadIdx.x;
    int edge = t >> 4;
    int ch = t & 15;
    if (edge >= n) return;
    int s = esrc[edge], d = edst[edge];
    uint4 ua = *(const uint4*)(hp + (size_t)s * HDIM + ch * 8);
    uint4 ub = *(const uint4*)(hr + (size_t)d * HDIM + ch * 8);
    float al, ah, bl, bh;
    float v = 0.f;
    unpack2(ua.x, al, ah); unpack2(ub.x, bl, bh); v += al * bl + ah * bh;
    unpack2(ua.y, al, ah); unpack2(ub.y, bl, bh); v += al * bl + ah * bh;
    unpack2(ua.z, al, ah); unpack2(ub.z, bl, bh); v += al * bl + ah * bh;
    unpack2(ua.w, al, ah); unpack2(ub.w, bl, bh); v += al * bl + ah * bh;
    v += __shfl_xor(v, 8);
    v += __shfl_xor(v, 4);
    v += __shfl_xor(v, 2);
    v += __shfl_xor(v, 1);
    if (ch == 0) out[edge] = v;
}

// ---------------- launch ----------------

extern "C" void kernel_launch(void* const* d_in, const int* in_sizes, int n_in,
                              void* d_out, int out_size, void* d_ws, size_t ws_size,
                              hipStream_t stream) {
    const float* x_pep   = (const float*)d_in[0];
    const float* x_prot  = (const float*)d_in[1];
    const int*   e_src   = (const int*)d_in[2];
    const int*   e_dst   = (const int*)d_in[3];
    const int*   el_src  = (const int*)d_in[4];
    const int*   el_dst  = (const int*)d_in[5];
    const float* W_pep   = (const float*)d_in[6];
    const float* b_pep   = (const float*)d_in[7];
    const float* W_prot  = (const float*)d_in[8];
    const float* b_prot  = (const float*)d_in[9];
    const float* Wl1_bind = (const float*)d_in[10];
    const float* Wr1_bind = (const float*)d_in[11];
    const float* Wl1_rev  = (const float*)d_in[12];
    const float* Wr1_rev  = (const float*)d_in[13];
    const float* Wl2_bind = (const float*)d_in[14];
    const float* Wr2_bind = (const float*)d_in[15];
    const float* Wl2_rev  = (const float*)d_in[16];
    const float* Wr2_rev  = (const float*)d_in[17];
    const float* b1_bind  = (const float*)d_in[18];
    const float* b1_rev   = (const float*)d_in[19];
    const float* b2_bind  = (const float*)d_in[20];
    const float* b2_rev   = (const float*)d_in[21];
    float* out = (float*)d_out;

    // workspace: bf16 node tables, then CSR ints, staging, bin matrices
    ushort* P0 = (ushort*)d_ws;
    ushort* P1 = P0 + (size_t)NP_PEP * HDIM;
    ushort* R0 = P1 + (size_t)NP_PEP * HDIM;
    ushort* R1 = R0 + (size_t)NP_PROT * HDIM;
    int* cnt_pep     = (int*)(R1 + (size_t)NP_PROT * HDIM);
    int* cnt_prot    = cnt_pep + NP_PEP;
    int* rowptr_pep  = cnt_prot + NP_PROT;
    int* rowptr_prot = rowptr_pep + NP_PEP + 1;
    int* cur_pep     = rowptr_prot + NP_PROT + 1;
    int* cur_prot    = cur_pep + NP_PEP;
    int* col_pep     = cur_prot + NP_PROT;
    int* col_prot    = col_pep + NE;
    uint* stagP      = (uint*)(col_prot + NE);   // pep-bucketed staging
    uint* stagQ      = stagP + NE;               // prot-bucketed staging
    int* Gq          = (int*)(stagQ + NE);       // [NBQ][NBLK]
    int* Oq          = Gq + NBQ * NBLK;
    int* Gp          = Oq + NBQ * NBLK;          // [NBP][NBLK]
    int* Op          = Gp + NBP * NBLK;

    // ---- CSR build (binned two-pass, no per-edge global atomics) ----
    zero_i32<<<(NP_PEP + NP_PROT + 255) / 256, 256, 0, stream>>>(cnt_pep, NP_PEP + NP_PROT);
    hist_kernel<<<(NE + 255) / 256, 256, 0, stream>>>(e_src, e_dst, cnt_pep, cnt_prot, NE);
    scan_kernel<<<1, 1024, 0, stream>>>(cnt_pep, rowptr_pep, cur_pep, NP_PEP);
    scan_kernel<<<1, 1024, 0, stream>>>(cnt_prot, rowptr_prot, cur_prot, NP_PROT);
    bin_count<<<NBLK, 512, 0, stream>>>(e_src, e_dst, Gq, Gp);
    bucket_offsets<<<NBQ, 512, 0, stream>>>(rowptr_prot, Gq, Oq, 16);
    bucket_offsets<<<NBP, 512, 0, stream>>>(rowptr_pep, Gp, Op, 128);
    bin_scatter<<<NBLK, 512, 0, stream>>>(e_src, e_dst, Oq, stagQ, SHQ, 1);
    bin_scatter<<<NBLK, 512, 0, stream>>>(e_src, e_dst, Op, stagP, SHP, 0);
    bin_place<<<NBQ, 256, 0, stream>>>(stagQ, rowptr_prot, col_prot, NP_PROT, 16, 1);
    bin_place<<<NBP, 256, 0, stream>>>(stagP, rowptr_pep, col_pep, NP_PEP, 128, 0);

    // ---- input projections (fp32 in, bf16 out, MFMA) ----
    gemm_proj_mfma<<<(NP_PEP + 127) / 128, 256, 0, stream>>>(x_pep, W_pep, b_pep, P0, NP_PEP, F_IN);
    gemm_proj_mfma<<<(NP_PROT + 127) / 128, 256, 0, stream>>>(x_prot, W_prot, b_prot, R0, NP_PROT, F_IN);

    // ---- SAGE layer 1 (+relu) ----
    aggr_mean_bf16<<<(NP_PROT + 3) / 4, 256, 0, stream>>>(P0, rowptr_prot, col_prot, R1, NP_PROT);
    aggr_mean_bf16<<<(NP_PEP + 3) / 4, 256, 0, stream>>>(R0, rowptr_pep, col_pep, P1, NP_PEP);
    lin2_mfma<<<(NP_PROT + 127) / 128, 256, 0, stream>>>(R1, Wl1_bind, R0, Wr1_bind, b1_bind,
                                                         R1, NP_PROT, 1);
    lin2_mfma<<<(NP_PEP + 127) / 128, 256, 0, stream>>>(P1, Wl1_rev, P0, Wr1_rev, b1_rev,
                                                        P1, NP_PEP, 1);

    // ---- SAGE layer 2 ----
    aggr_mean_bf16<<<(NP_PROT + 3) / 4, 256, 0, stream>>>(P1, rowptr_prot, col_prot, R0, NP_PROT);
    aggr_mean_bf16<<<(NP_PEP + 3) / 4, 256, 0, stream>>>(R1, rowptr_pep, col_pep, P0, NP_PEP);
    lin2_mfma<<<(NP_PROT + 127) / 128, 256, 0, stream>>>(R0, Wl2_bind, R1, Wr2_bind, b2_bind,
                                                         R0, NP_PROT, 0);
    lin2_mfma<<<(NP_PEP + 127) / 128, 256, 0, stream>>>(P0, Wl2_rev, P1, Wr2_rev, b2_rev,
                                                        P0, NP_PEP, 0);

    // ---- classifier ----
    classify_bf16<<<(NEL * 16 + 255) / 256, 256, 0, stream>>>(P0, R0, el_src, el_dst, out, NEL);
}

// Round 4
// 785.572 us; speedup vs baseline: 2.0972x; 1.3140x over previous
//
#include <hip/hip_runtime.h>
#include <hip/hip_bf16.h>
#include <cstdint>

#define NP_PEP 50000
#define NP_PROT 8000
#define NE 1600000
#define NEL 200000
#define F_IN 1280
#define HDIM 128

// CSR binning constants
#define CHUNK 4096
#define NBLK 391            // ceil(NE/CHUNK)
#define NBQ 500             // prot buckets (16 nodes each, d>>4)
#define SHQ 4
#define NPBQ 16
#define NBP 391             // pep buckets (128 nodes each, s>>7)
#define SHP 7
#define NPBP 128

typedef __attribute__((ext_vector_type(8))) short bfrag;   // 8 bf16 (4 VGPRs)
typedef __attribute__((ext_vector_type(4))) short bhalf4;  // 4 bf16 (8 B)
typedef __attribute__((ext_vector_type(4))) float f32x4;

__device__ inline ushort f2bf(float x) {            // RNE round fp32->bf16
    union { float f; uint u; } v; v.f = x;
    uint r = v.u + 0x7FFFu + ((v.u >> 16) & 1u);
    return (ushort)(r >> 16);
}
__device__ inline void unpack2(uint u, float& lo, float& hi) {
    union { uint u; float f; } a, b;
    a.u = u << 16; b.u = u & 0xffff0000u;
    lo = a.f; hi = b.f;
}
__device__ inline uint pack2(float a, float b) {
    return (uint)f2bf(a) | ((uint)f2bf(b) << 16);
}

// ---------------- CSR build (bucket-local, no per-node global atomics) ----------------

// per-block bucket histograms for both directions; G layout [bucket][block]
__global__ __launch_bounds__(512) void bin_count(const int* __restrict__ esrc,
                                                 const int* __restrict__ edst,
                                                 int* __restrict__ Gq,   // [NBQ][NBLK]
                                                 int* __restrict__ Gp) { // [NBP][NBLK]
    __shared__ int hq[NBQ];
    __shared__ int hp[NBP];
    int b = blockIdx.x, t = threadIdx.x;
    if (t < NBQ) hq[t] = 0;
    if (t < NBP) hp[t] = 0;
    __syncthreads();
    int e0 = b * CHUNK, cnt = min(CHUNK, NE - e0);
#pragma unroll
    for (int r = 0; r < 8; ++r) {
        int i = t + r * 512;
        if (i < cnt) {
            atomicAdd(&hq[edst[e0 + i] >> SHQ], 1);
            atomicAdd(&hp[esrc[e0 + i] >> SHP], 1);
        }
    }
    __syncthreads();
    if (t < NBQ) Gq[t * NBLK + b] = hq[t];
    if (t < NBP) Gp[t * NBLK + b] = hp[t];
}

// per-bucket exclusive scan over blocks (relative) + bucket totals
__global__ __launch_bounds__(512) void rel_offsets(const int* __restrict__ Gq,
                                                   int* __restrict__ Oq, int* __restrict__ Tq,
                                                   const int* __restrict__ Gp,
                                                   int* __restrict__ Op, int* __restrict__ Tp) {
    const int* G; int* O; int* T; int j;
    if (blockIdx.x < NBQ) { G = Gq; O = Oq; T = Tq; j = blockIdx.x; }
    else                  { G = Gp; O = Op; T = Tp; j = blockIdx.x - NBQ; }
    __shared__ int sh[512];
    int t = threadIdx.x;
    int v = (t < NBLK) ? G[j * NBLK + t] : 0;
    sh[t] = v;
    __syncthreads();
    for (int off = 1; off < 512; off <<= 1) {
        int a = sh[t];
        int c = (t >= off) ? sh[t - off] : 0;
        __syncthreads();
        sh[t] = a + c;
        __syncthreads();
    }
    if (t < NBLK) O[j * NBLK + t] = sh[t] - v;
    if (t == 511) T[j] = sh[511];
}

// bucket bases: exclusive scan of totals for both directions (tiny)
__global__ __launch_bounds__(512) void base_scan(const int* __restrict__ Tq, int* __restrict__ Bq,
                                                 const int* __restrict__ Tp, int* __restrict__ Bp) {
    __shared__ int sh[512];
    int t = threadIdx.x;
    int v = (t < NBQ) ? Tq[t] : 0;
    sh[t] = v;
    __syncthreads();
    for (int off = 1; off < 512; off <<= 1) {
        int a = sh[t];
        int c = (t >= off) ? sh[t - off] : 0;
        __syncthreads();
        sh[t] = a + c;
        __syncthreads();
    }
    if (t < NBQ) Bq[t] = sh[t] - v;
    if (t == 0) Bq[NBQ] = NE;
    __syncthreads();
    int v2 = (t < NBP) ? Tp[t] : 0;
    sh[t] = v2;
    __syncthreads();
    for (int off = 1; off < 512; off <<= 1) {
        int a = sh[t];
        int c = (t >= off) ? sh[t - off] : 0;
        __syncthreads();
        sh[t] = a + c;
        __syncthreads();
    }
    if (t < NBP) Bp[t] = sh[t] - v2;
    if (t == 0) Bp[NBP] = NE;
}

// fused both-direction LDS counting sort of 4096-edge chunks; coalesced copy-out
__global__ __launch_bounds__(512) void bin_scatter2(const int* __restrict__ esrc,
                                                    const int* __restrict__ edst,
                                                    const int* __restrict__ Oq,
                                                    const int* __restrict__ Bq,
                                                    const int* __restrict__ Op,
                                                    const int* __restrict__ Bp,
                                                    uint* __restrict__ stagQ,
                                                    uint* __restrict__ stagP) {
    __shared__ int hist[512];
    __shared__ int start[512];
    __shared__ uint sorted[CHUNK];
    int b = blockIdx.x, t = threadIdx.x;
    int e0 = b * CHUNK, cnt = min(CHUNK, NE - e0);
    uint pk[8];
    bool val[8];
#pragma unroll
    for (int r = 0; r < 8; ++r) {
        int i = t + r * 512;
        val[r] = (i < cnt);
        if (val[r]) {
            int s = esrc[e0 + i], d = edst[e0 + i];
            pk[r] = ((uint)s << 13) | (uint)d;
        }
    }
    for (int dir = 0; dir < 2; ++dir) {
        const int* O = dir ? Op : Oq;
        const int* B = dir ? Bp : Bq;
        uint* stg = dir ? stagP : stagQ;
        int shf = dir ? SHP : SHQ;
        hist[t] = 0;
        __syncthreads();
        int bk[8];
#pragma unroll
        for (int r = 0; r < 8; ++r) {
            bk[r] = -1;
            if (val[r]) {
                int key = dir ? (int)(pk[r] >> 13) : (int)(pk[r] & 8191u);
                bk[r] = key >> shf;
                atomicAdd(&hist[bk[r]], 1);
            }
        }
        __syncthreads();
        int ownv = hist[t];
        start[t] = ownv;
        __syncthreads();
        for (int off = 1; off < 512; off <<= 1) {
            int a = start[t];
            int c = (t >= off) ? start[t - off] : 0;
            __syncthreads();
            start[t] = a + c;
            __syncthreads();
        }
        int excl = start[t] - ownv;
        start[t] = excl;
        hist[t] = excl;
        __syncthreads();
#pragma unroll
        for (int r = 0; r < 8; ++r)
            if (bk[r] >= 0) {
                int rank = atomicAdd(&hist[bk[r]], 1);
                sorted[rank] = pk[r];
            }
        __syncthreads();
#pragma unroll
        for (int r = 0; r < 8; ++r) {
            int i = t + r * 512;
            if (i < cnt) {
                uint v = sorted[i];
                int key = dir ? (int)(v >> 13) : (int)(v & 8191u);
                int bb = key >> shf;
                stg[B[bb] + O[bb * NBLK + b] + (i - start[bb])] = v;
            }
        }
        __syncthreads();
    }
}

// per-bucket: LDS node histogram -> scan -> rowptr + col placement (LDS cursors only)
__global__ __launch_bounds__(256) void finalize_csr(const uint* __restrict__ stagQ,
                                                    const int* __restrict__ Bq,
                                                    int* __restrict__ rowptr_prot,
                                                    int* __restrict__ col_prot,
                                                    const uint* __restrict__ stagP,
                                                    const int* __restrict__ Bp,
                                                    int* __restrict__ rowptr_pep,
                                                    int* __restrict__ col_pep) {
    __shared__ int cnts[128];
    __shared__ int sc[128];
    __shared__ int cur[128];
    const uint* stg; const int* B; int* rowptr; int* col;
    int n, npb, j, use_dst;
    if (blockIdx.x < NBQ) {
        stg = stagQ; B = Bq; rowptr = rowptr_prot; col = col_prot;
        n = NP_PROT; npb = NPBQ; j = blockIdx.x; use_dst = 1;
    } else {
        stg = stagP; B = Bp; rowptr = rowptr_pep; col = col_pep;
        n = NP_PEP; npb = NPBP; j = blockIdx.x - NBQ; use_dst = 0;
    }
    int t = threadIdx.x;
    int first = j * npb;
    int nn = min(npb, n - first);
    if (t < 128) cnts[t] = 0;
    __syncthreads();
    int s0 = B[j], s1 = B[j + 1];
    for (int i = s0 + t; i < s1; i += 256) {
        uint v = stg[i];
        int key = use_dst ? (int)(v & 8191u) : (int)(v >> 13);
        atomicAdd(&cnts[key - first], 1);
    }
    __syncthreads();
    int v = 0;
    if (t < 128) { v = cnts[t]; sc[t] = v; }
    __syncthreads();
    for (int off = 1; off < 128; off <<= 1) {
        int a = 0, c = 0;
        if (t < 128) { a = sc[t]; c = (t >= off) ? sc[t - off] : 0; }
        __syncthreads();
        if (t < 128) sc[t] = a + c;
        __syncthreads();
    }
    if (t < nn) {
        int excl = sc[t] - v;
        rowptr[first + t] = s0 + excl;
        cur[t] = s0 + excl;
    }
    if (t == 0 && j == 0) rowptr[n] = NE;
    __syncthreads();
    for (int i = s0 + t; i < s1; i += 256) {
        uint v2 = stg[i];
        int key, pay;
        if (use_dst) { key = (int)(v2 & 8191u); pay = (int)(v2 >> 13); }
        else         { key = (int)(v2 >> 13);   pay = (int)(v2 & 8191u); }
        int pos = atomicAdd(&cur[key - first], 1);
        col[pos] = pay;
    }
}

// ---- shared W staging: W[k0..k0+32)[0..128) fp32 -> bf16 B-fragment layout ----
__device__ inline void stage_W(const float* __restrict__ W, ushort* Blds, int k0, int tid) {
    int n = tid & 127, g = tid >> 7;
#pragma unroll
    for (int hh = 0; hh < 2; ++hh) {
        int h = g + hh * 2;
        const float* wp = W + (size_t)(k0 + h * 8) * HDIM + n;
        bfrag p;
#pragma unroll
        for (int j = 0; j < 8; ++j) p[j] = (short)f2bf(wp[(size_t)j * HDIM]);
        *(bfrag*)&Blds[((n >> 4) * 64 + (h << 4) + (n & 15)) * 8] = p;
    }
}

// -------- projection: C[M,128](bf16) = A[M,K](f32) @ W[K,128](f32) + b --------
__global__ __launch_bounds__(256) void gemm_proj_mfma(const float* __restrict__ A,
                                                      const float* __restrict__ W,
                                                      const float* __restrict__ bias,
                                                      ushort* __restrict__ Cg,
                                                      int M, int K) {
    __shared__ ushort Alds[4096];
    __shared__ ushort Blds[4096];
    __shared__ ushort Clds[128 * 136];
    int tid = threadIdx.x;
    int lane = tid & 63, w = tid >> 6, wm = w >> 1, wn = w & 1;
    int r0 = blockIdx.x * 128;

    f32x4 acc[4][4];
#pragma unroll
    for (int i = 0; i < 4; ++i)
#pragma unroll
        for (int j = 0; j < 4; ++j) acc[i][j] = (f32x4){0.f, 0.f, 0.f, 0.f};

    for (int k0 = 0; k0 < K; k0 += 32) {
#pragma unroll
        for (int i = 0; i < 4; ++i) {
            int idx = tid + 256 * i;
            int row = idx >> 3, q = idx & 7;
            int gr = min(r0 + row, M - 1);
            float4 v = *(const float4*)(A + (size_t)gr * K + k0 + q * 4);
            bhalf4 p;
            p.x = (short)f2bf(v.x); p.y = (short)f2bf(v.y);
            p.z = (short)f2bf(v.z); p.w = (short)f2bf(v.w);
            int off = ((row >> 4) * 64 + ((q >> 1) << 4) + (row & 15)) * 8 + (q & 1) * 4;
            *(bhalf4*)&Alds[off] = p;
        }
        stage_W(W, Blds, k0, tid);
        __syncthreads();
        const bfrag* Af = (const bfrag*)Alds;
        const bfrag* Bf = (const bfrag*)Blds;
        bfrag af[4], bf_[4];
#pragma unroll
        for (int i = 0; i < 4; ++i) af[i] = Af[(wm * 4 + i) * 64 + lane];
#pragma unroll
        for (int j = 0; j < 4; ++j) bf_[j] = Bf[(wn * 4 + j) * 64 + lane];
#pragma unroll
        for (int i = 0; i < 4; ++i)
#pragma unroll
            for (int j = 0; j < 4; ++j)
                acc[i][j] = __builtin_amdgcn_mfma_f32_16x16x32_bf16(af[i], bf_[j], acc[i][j], 0, 0, 0);
        __syncthreads();
    }
#pragma unroll
    for (int j = 0; j < 4; ++j) {
        int colL = wn * 64 + j * 16 + (lane & 15);
        float bcol = bias[colL];
#pragma unroll
        for (int i = 0; i < 4; ++i) {
            int rbase = wm * 64 + i * 16 + ((lane >> 4) << 2);
            f32x4 v = acc[i][j];
            Clds[(rbase + 0) * 136 + colL] = f2bf(v.x + bcol);
            Clds[(rbase + 1) * 136 + colL] = f2bf(v.y + bcol);
            Clds[(rbase + 2) * 136 + colL] = f2bf(v.z + bcol);
            Clds[(rbase + 3) * 136 + colL] = f2bf(v.w + bcol);
        }
    }
    __syncthreads();
#pragma unroll
    for (int c = 0; c < 8; ++c) {
        int cidx = c * 256 + tid;
        int row = cidx >> 4, h = cidx & 15;
        int gr = r0 + row;
        if (gr < M)
            *(bfrag*)(Cg + (size_t)gr * HDIM + h * 8) = *(const bfrag*)&Clds[row * 136 + h * 8];
    }
}

// ---- fused linear (bf16): C = A1@W1 + A2@W2 + b (+relu). C may alias A1. ----
__global__ __launch_bounds__(256) void lin2_mfma(const ushort* A1,
                                                 const float* __restrict__ W1,
                                                 const ushort* A2,
                                                 const float* __restrict__ W2,
                                                 const float* __restrict__ bias,
                                                 ushort* C, int M, int do_relu) {
    __shared__ ushort Alds[4096];
    __shared__ ushort Blds[4096];
    __shared__ ushort Clds[128 * 136];
    int tid = threadIdx.x;
    int lane = tid & 63, w = tid >> 6, wm = w >> 1, wn = w & 1;
    int r0 = blockIdx.x * 128;

    f32x4 acc[4][4];
#pragma unroll
    for (int i = 0; i < 4; ++i)
#pragma unroll
        for (int j = 0; j < 4; ++j) acc[i][j] = (f32x4){0.f, 0.f, 0.f, 0.f};

    for (int kt = 0; kt < 8; ++kt) {
        const ushort* A = (kt < 4) ? A1 : A2;
        const float* Wm = (kt < 4) ? W1 : W2;
        int k0 = (kt & 3) * 32;
#pragma unroll
        for (int i = 0; i < 2; ++i) {
            int idx = tid + 256 * i;
            int row = idx >> 2, h = idx & 3;
            int gr = min(r0 + row, M - 1);
            *(bfrag*)&Alds[((row >> 4) * 64 + (h << 4) + (row & 15)) * 8] =
                *(const bfrag*)(A + (size_t)gr * HDIM + k0 + h * 8);
        }
        stage_W(Wm, Blds, k0, tid);
        __syncthreads();
        const bfrag* Af = (const bfrag*)Alds;
        const bfrag* Bf = (const bfrag*)Blds;
        bfrag af[4], bf_[4];
#pragma unroll
        for (int i = 0; i < 4; ++i) af[i] = Af[(wm * 4 + i) * 64 + lane];
#pragma unroll
        for (int j = 0; j < 4; ++j) bf_[j] = Bf[(wn * 4 + j) * 64 + lane];
#pragma unroll
        for (int i = 0; i < 4; ++i)
#pragma unroll
            for (int j = 0; j < 4; ++j)
                acc[i][j] = __builtin_amdgcn_mfma_f32_16x16x32_bf16(af[i], bf_[j], acc[i][j], 0, 0, 0);
        __syncthreads();
    }
#pragma unroll
    for (int j = 0; j < 4; ++j) {
        int colL = wn * 64 + j * 16 + (lane & 15);
        float bcol = bias[colL];
#pragma unroll
        for (int i = 0; i < 4; ++i) {
            int rbase = wm * 64 + i * 16 + ((lane >> 4) << 2);
            f32x4 v = acc[i][j];
            float o0 = v.x + bcol, o1 = v.y + bcol, o2 = v.z + bcol, o3 = v.w + bcol;
            if (do_relu) {
                o0 = fmaxf(o0, 0.f); o1 = fmaxf(o1, 0.f);
                o2 = fmaxf(o2, 0.f); o3 = fmaxf(o3, 0.f);
            }
            Clds[(rbase + 0) * 136 + colL] = f2bf(o0);
            Clds[(rbase + 1) * 136 + colL] = f2bf(o1);
            Clds[(rbase + 2) * 136 + colL] = f2bf(o2);
            Clds[(rbase + 3) * 136 + colL] = f2bf(o3);
        }
    }
    __syncthreads();
#pragma unroll
    for (int c = 0; c < 8; ++c) {
        int cidx = c * 256 + tid;
        int row = cidx >> 4, h = cidx & 15;
        int gr = r0 + row;
        if (gr < M)
            *(bfrag*)(C + (size_t)gr * HDIM + h * 8) = *(const bfrag*)&Clds[row * 136 + h * 8];
    }
}

// ------- mean aggregation (bf16 tables): one wave per dst node, 4 edges/iter -------
__global__ __launch_bounds__(256) void aggr_mean_bf16(const ushort* __restrict__ Hsrc,
                                                      const int* __restrict__ rowptr,
                                                      const int* __restrict__ col,
                                                      ushort* __restrict__ Mout, int Ndst) {
    int node = blockIdx.x * 4 + (threadIdx.x >> 6);
    if (node >= Ndst) return;
    int lane = threadIdx.x & 63;
    int sub = lane >> 4;
    int ch = lane & 15;
    int beg = rowptr[node], end = rowptr[node + 1];
    int deg = end - beg;
    float a0 = 0, a1 = 0, a2 = 0, a3 = 0, a4 = 0, a5 = 0, a6 = 0, a7 = 0;
    for (int j = beg + sub; j < end; j += 4) {
        int idx = col[j];
        uint4 u = *(const uint4*)(Hsrc + (size_t)idx * HDIM + ch * 8);
        float lo, hi;
        unpack2(u.x, lo, hi); a0 += lo; a1 += hi;
        unpack2(u.y, lo, hi); a2 += lo; a3 += hi;
        unpack2(u.z, lo, hi); a4 += lo; a5 += hi;
        unpack2(u.w, lo, hi); a6 += lo; a7 += hi;
    }
    a0 += __shfl_xor(a0, 16); a0 += __shfl_xor(a0, 32);
    a1 += __shfl_xor(a1, 16); a1 += __shfl_xor(a1, 32);
    a2 += __shfl_xor(a2, 16); a2 += __shfl_xor(a2, 32);
    a3 += __shfl_xor(a3, 16); a3 += __shfl_xor(a3, 32);
    a4 += __shfl_xor(a4, 16); a4 += __shfl_xor(a4, 32);
    a5 += __shfl_xor(a5, 16); a5 += __shfl_xor(a5, 32);
    a6 += __shfl_xor(a6, 16); a6 += __shfl_xor(a6, 32);
    a7 += __shfl_xor(a7, 16); a7 += __shfl_xor(a7, 32);
    if (sub == 0) {
        float inv = 1.0f / (float)max(deg, 1);
        uint4 o;
        o.x = pack2(a0 * inv, a1 * inv);
        o.y = pack2(a2 * inv, a3 * inv);
        o.z = pack2(a4 * inv, a5 * inv);
        o.w = pack2(a6 * inv, a7 * inv);
        *(uint4*)(Mout + (size_t)node * HDIM + ch * 8) = o;
    }
}

// ---------------- classifier (bf16 tables): 16 lanes per edge ----------------
__global__ __launch_bounds__(256) void classify_bf16(const ushort* __restrict__ hp,
                                                     const ushort* __restrict__ hr,
                                                     const int* __restrict__ esrc,
                                                     const int* __restrict__ edst,
                                                     float* __restrict__ out, int n) {
    int t = blockIdx.x * blockDim.x + threadIdx.x;
    int edge = t >> 4;
    int ch = t & 15;
    if (edge >= n) return;
    int s = esrc[edge], d = edst[edge];
    uint4 ua = *(const uint4*)(hp + (size_t)s * HDIM + ch * 8);
    uint4 ub = *(const uint4*)(hr + (size_t)d * HDIM + ch * 8);
    float al, ah, bl, bh;
    float v = 0.f;
    unpack2(ua.x, al, ah); unpack2(ub.x, bl, bh); v += al * bl + ah * bh;
    unpack2(ua.y, al, ah); unpack2(ub.y, bl, bh); v += al * bl + ah * bh;
    unpack2(ua.z, al, ah); unpack2(ub.z, bl, bh); v += al * bl + ah * bh;
    unpack2(ua.w, al, ah); unpack2(ub.w, bl, bh); v += al * bl + ah * bh;
    v += __shfl_xor(v, 8);
    v += __shfl_xor(v, 4);
    v += __shfl_xor(v, 2);
    v += __shfl_xor(v, 1);
    if (ch == 0) out[edge] = v;
}

// ---------------- launch ----------------

extern "C" void kernel_launch(void* const* d_in, const int* in_sizes, int n_in,
                              void* d_out, int out_size, void* d_ws, size_t ws_size,
                              hipStream_t stream) {
    const float* x_pep   = (const float*)d_in[0];
    const float* x_prot  = (const float*)d_in[1];
    const int*   e_src   = (const int*)d_in[2];
    const int*   e_dst   = (const int*)d_in[3];
    const int*   el_src  = (const int*)d_in[4];
    const int*   el_dst  = (const int*)d_in[5];
    const float* W_pep   = (const float*)d_in[6];
    const float* b_pep   = (const float*)d_in[7];
    const float* W_prot  = (const float*)d_in[8];
    const float* b_prot  = (const float*)d_in[9];
    const float* Wl1_bind = (const float*)d_in[10];
    const float* Wr1_bind = (const float*)d_in[11];
    const float* Wl1_rev  = (const float*)d_in[12];
    const float* Wr1_rev  = (const float*)d_in[13];
    const float* Wl2_bind = (const float*)d_in[14];
    const float* Wr2_bind = (const float*)d_in[15];
    const float* Wl2_rev  = (const float*)d_in[16];
    const float* Wr2_rev  = (const float*)d_in[17];
    const float* b1_bind  = (const float*)d_in[18];
    const float* b1_rev   = (const float*)d_in[19];
    const float* b2_bind  = (const float*)d_in[20];
    const float* b2_rev   = (const float*)d_in[21];
    float* out = (float*)d_out;

    // workspace layout
    ushort* P0 = (ushort*)d_ws;
    ushort* P1 = P0 + (size_t)NP_PEP * HDIM;
    ushort* R0 = P1 + (size_t)NP_PEP * HDIM;
    ushort* R1 = R0 + (size_t)NP_PROT * HDIM;
    int* rowptr_pep  = (int*)(R1 + (size_t)NP_PROT * HDIM);
    int* rowptr_prot = rowptr_pep + NP_PEP + 1;
    int* col_pep     = rowptr_prot + NP_PROT + 1;
    int* col_prot    = col_pep + NE;
    uint* stagP      = (uint*)(col_prot + NE);
    uint* stagQ      = stagP + NE;
    int* Gq          = (int*)(stagQ + NE);       // [NBQ][NBLK]
    int* Oq          = Gq + NBQ * NBLK;
    int* Gp          = Oq + NBQ * NBLK;          // [NBP][NBLK]
    int* Op          = Gp + NBP * NBLK;
    int* Tq          = Op + NBP * NBLK;
    int* Tp          = Tq + NBQ;
    int* Bq          = Tp + NBP;                 // NBQ+1
    int* Bp          = Bq + NBQ + 1;             // NBP+1

    // ---- CSR build: 5 launches, all histograms/scans/cursors bucket-local in LDS ----
    bin_count<<<NBLK, 512, 0, stream>>>(e_src, e_dst, Gq, Gp);
    rel_offsets<<<NBQ + NBP, 512, 0, stream>>>(Gq, Oq, Tq, Gp, Op, Tp);
    base_scan<<<1, 512, 0, stream>>>(Tq, Bq, Tp, Bp);
    bin_scatter2<<<NBLK, 512, 0, stream>>>(e_src, e_dst, Oq, Bq, Op, Bp, stagQ, stagP);
    finalize_csr<<<NBQ + NBP, 256, 0, stream>>>(stagQ, Bq, rowptr_prot, col_prot,
                                                stagP, Bp, rowptr_pep, col_pep);

    // ---- input projections (fp32 in, bf16 out, MFMA) ----
    gemm_proj_mfma<<<(NP_PEP + 127) / 128, 256, 0, stream>>>(x_pep, W_pep, b_pep, P0, NP_PEP, F_IN);
    gemm_proj_mfma<<<(NP_PROT + 127) / 128, 256, 0, stream>>>(x_prot, W_prot, b_prot, R0, NP_PROT, F_IN);

    // ---- SAGE layer 1 (+relu) ----
    aggr_mean_bf16<<<(NP_PROT + 3) / 4, 256, 0, stream>>>(P0, rowptr_prot, col_prot, R1, NP_PROT);
    aggr_mean_bf16<<<(NP_PEP + 3) / 4, 256, 0, stream>>>(R0, rowptr_pep, col_pep, P1, NP_PEP);
    lin2_mfma<<<(NP_PROT + 127) / 128, 256, 0, stream>>>(R1, Wl1_bind, R0, Wr1_bind, b1_bind,
                                                         R1, NP_PROT, 1);
    lin2_mfma<<<(NP_PEP + 127) / 128, 256, 0, stream>>>(P1, Wl1_rev, P0, Wr1_rev, b1_rev,
                                                        P1, NP_PEP, 1);

    // ---- SAGE layer 2 ----
    aggr_mean_bf16<<<(NP_PROT + 3) / 4, 256, 0, stream>>>(P1, rowptr_prot, col_prot, R0, NP_PROT);
    aggr_mean_bf16<<<(NP_PEP + 3) / 4, 256, 0, stream>>>(R1, rowptr_pep, col_pep, P0, NP_PEP);
    lin2_mfma<<<(NP_PROT + 127) / 128, 256, 0, stream>>>(R0, Wl2_bind, R1, Wr2_bind, b2_bind,
                                                         R0, NP_PROT, 0);
    lin2_mfma<<<(NP_PEP + 127) / 128, 256, 0, stream>>>(P0, Wl2_rev, P1, Wr2_rev, b2_rev,
                                                        P0, NP_PEP, 0);

    // ---- classifier ----
    classify_bf16<<<(NEL * 16 + 255) / 256, 256, 0, stream>>>(P0, R0, el_src, el_dst, out, NEL);
}